// Round 4
// baseline (391.785 us; speedup 1.0000x reference)
//
#include <hip/hip_runtime.h>

// Instant-NGP hash-grid trilinear interp — approximate spatial binning edition.
//
// R2 evidence: gather is bound by the L2-miss stream (612 MB FETCH @ 3.2 TB/s,
// VALUBusy 7%). R3 evidence: full counting-sort captures the reuse (main
// kernel ~100 us) but its scatter (random float4 writes, 4x write
// amplification, 126 MB WRITE @ 780 GB/s) cost 181 us alone.
// This version keeps the reorder but makes it cheap:
//   - fixed-capacity Morton bins (no hist, no scans, 2 fewer launches)
//   - scatter stores 4 B indices into per-bin sequential slots (writes merge
//     in L2; no amplification)
//   - main kernel: 1 block per bin, 2 threads per point, XCD-chunked Morton
//     ranges so the 8 private L2s don't duplicate row fetches.
// Overflow list keeps it correct for any input distribution. Per-point math
// is bit-identical to the verified R1 kernel and independent of bin order.

#define TILE_SHIFT 3                 // tile = 8^3 cells
#define MDIM 32                      // Morton dims (tiles/dim = 25 <= 32)
#define NBINS (MDIM * MDIM * MDIM)   // 32768
#define CAP 192                      // slots per bin (avg occupancy 128)
#define MAIN_BLOCK 384               // CAP * 2 threads

__device__ __forceinline__ unsigned part1by2(unsigned x) {
    x &= 0x3Fu;
    x = (x | (x << 16)) & 0x030000FFu;
    x = (x | (x << 8))  & 0x0300F00Fu;
    x = (x | (x << 4))  & 0x030C30C3u;
    x = (x | (x << 2))  & 0x09249249u;
    return x;
}

__device__ __forceinline__ unsigned point_bin(float px, float py, float pz) {
    float qx = px / 0.005f, qy = py / 0.005f, qz = pz / 0.005f;
    int cx = (int)floorf(qx), cy = (int)floorf(qy), cz = (int)floorf(qz);
    unsigned tx = ((unsigned)cx) >> TILE_SHIFT;
    unsigned ty = ((unsigned)cy) >> TILE_SHIFT;
    unsigned tz = ((unsigned)cz) >> TILE_SHIFT;
    tx = min(tx, (unsigned)(MDIM - 1));   // safety clamp (order-only effect)
    ty = min(ty, (unsigned)(MDIM - 1));
    tz = min(tz, (unsigned)(MDIM - 1));
    return part1by2(tx) | (part1by2(ty) << 1) | (part1by2(tz) << 2);
}

// Core per-point math — identical to the verified R1 kernel.
__device__ __forceinline__ void interp_point(
    int i, unsigned h, const float* __restrict__ pts,
    const float4* __restrict__ feat4, float4* __restrict__ out4,
    unsigned buckets, int is_pow2)
{
    float px = pts[3*i], py = pts[3*i+1], pz = pts[3*i+2];
    float qx = px / 0.005f, qy = py / 0.005f, qz = pz / 0.005f;
    float bx = floorf(qx), by = floorf(qy), bz = floorf(qz);
    float fx = qx - bx, fy = qy - by, fz = qz - bz;
    unsigned ux = (unsigned)(int)bx, uy = (unsigned)(int)by, uz = (unsigned)(int)bz;
    unsigned hx0 = ux, hx1 = ux + 1u;
    unsigned hy0 = uy * 2654435761u, hy1 = (uy + 1u) * 2654435761u;
    unsigned hz0 = uz * 805459861u,  hz1 = (uz + 1u) * 805459861u;
    unsigned hsh[8] = {
        hx0 ^ hy0 ^ hz0, hx1 ^ hy0 ^ hz0,
        hx0 ^ hy1 ^ hz0, hx1 ^ hy1 ^ hz0,
        hx0 ^ hy0 ^ hz1, hx1 ^ hy0 ^ hz1,
        hx0 ^ hy1 ^ hz1, hx1 ^ hy1 ^ hz1,
    };
    unsigned off[8];
    if (is_pow2) {
        unsigned mask = buckets - 1u;
        #pragma unroll
        for (int c = 0; c < 8; ++c) off[c] = (hsh[c] & mask) * 2u + h;
    } else {
        #pragma unroll
        for (int c = 0; c < 8; ++c) off[c] = (hsh[c] % buckets) * 2u + h;
    }
    float4 f[8];
    #pragma unroll
    for (int c = 0; c < 8; ++c) f[c] = feat4[off[c]];
    float wx0 = 1.0f - fx, wx1 = fx;
    float wy0 = 1.0f - fy, wy1 = fy;
    float wz0 = 1.0f - fz, wz1 = fz;
    float w[8] = {
        (wx0 * wy0) * wz0, (wx1 * wy0) * wz0,
        (wx0 * wy1) * wz0, (wx1 * wy1) * wz0,
        (wx0 * wy0) * wz1, (wx1 * wy0) * wz1,
        (wx0 * wy1) * wz1, (wx1 * wy1) * wz1,
    };
    float4 a = make_float4(0.f, 0.f, 0.f, 0.f);
    #pragma unroll
    for (int c = 0; c < 8; ++c) {
        a.x += w[c] * f[c].x;
        a.y += w[c] * f[c].y;
        a.z += w[c] * f[c].z;
        a.w += w[c] * f[c].w;
    }
    out4[(size_t)i * 2u + h] = a;
}

// Scatter: bin each point, append its index to the bin's slot list (4 B write,
// sequential within bin -> merges in L2). Overflow -> list.
__global__ __launch_bounds__(256) void scatter_bin_kernel(
    const float* __restrict__ pts, unsigned* __restrict__ count,
    unsigned* __restrict__ ocount, unsigned* __restrict__ slots,
    unsigned* __restrict__ ovf, int N)
{
    int i = blockIdx.x * blockDim.x + threadIdx.x;
    if (i >= N) return;
    unsigned b = point_bin(pts[3*i], pts[3*i+1], pts[3*i+2]);
    unsigned pos = atomicAdd(&count[b], 1u);
    if (pos < CAP) {
        slots[b * CAP + pos] = (unsigned)i;
    } else {
        unsigned o = atomicAdd(ocount, 1u);
        ovf[o] = (unsigned)i;
    }
}

// Main: one block per Morton bin, 2 threads per point (paired 16 B halves).
__global__ __launch_bounds__(MAIN_BLOCK) void main_sorted_kernel(
    const float* __restrict__ pts, const unsigned* __restrict__ count,
    const unsigned* __restrict__ slots, const float4* __restrict__ feat4,
    float4* __restrict__ out4, unsigned buckets, int is_pow2)
{
    // Bijective XCD-chunk swizzle over NBINS (divisible by 8): each XCD gets a
    // contiguous Morton range -> compact spatial slab per private L2.
    int orig = blockIdx.x;
    int bin = (orig & 7) * (NBINS / 8) + (orig >> 3);

    unsigned cnt = count[bin];
    cnt = min(cnt, (unsigned)CAP);
    unsigned s = threadIdx.x >> 1;
    unsigned h = threadIdx.x & 1;
    if (s >= cnt) return;
    int i = (int)slots[bin * CAP + s];
    interp_point(i, h, pts, feat4, out4, buckets, is_pow2);
}

// Overflow cleanup (normally 0 points): grid-stride over the overflow list.
__global__ __launch_bounds__(256) void overflow_kernel(
    const float* __restrict__ pts, const unsigned* __restrict__ ocount,
    const unsigned* __restrict__ ovf, const float4* __restrict__ feat4,
    float4* __restrict__ out4, unsigned buckets, int is_pow2)
{
    unsigned oc = *ocount;
    unsigned total = oc * 2u;
    unsigned stride = gridDim.x * blockDim.x;
    for (unsigned t = blockIdx.x * blockDim.x + threadIdx.x; t < total; t += stride) {
        int i = (int)ovf[t >> 1];
        interp_point(i, t & 1u, pts, feat4, out4, buckets, is_pow2);
    }
}

// Fallback (verified R1 kernel) if ws is too small.
__global__ __launch_bounds__(256) void ngp_hash_interp2(
    const float* __restrict__ pts, const float4* __restrict__ feat4,
    float4* __restrict__ out4, int N, unsigned buckets, int is_pow2)
{
    int t = blockIdx.x * blockDim.x + threadIdx.x;
    int i = t >> 1;
    unsigned h = (unsigned)(t & 1);
    if (i >= N) return;
    interp_point(i, h, pts, feat4, out4, buckets, is_pow2);
}

extern "C" void kernel_launch(void* const* d_in, const int* in_sizes, int n_in,
                              void* d_out, int out_size, void* d_ws, size_t ws_size,
                              hipStream_t stream) {
    const float* pts    = (const float*)d_in[0];
    const float4* feat4 = (const float4*)d_in[1];
    float4* out4 = (float4*)d_out;

    int N = in_sizes[0] / 3;
    unsigned buckets = (unsigned)(in_sizes[1] / 8);
    int is_pow2 = ((buckets & (buckets - 1u)) == 0u) ? 1 : 0;

    // ws layout: count u32[NBINS] | ocount u32 (+pad) | slots u32[NBINS*CAP]
    //            | ovf u32[N]
    const size_t off_count = 0;
    const size_t off_oc    = (size_t)NBINS * 4;                 // 131072
    const size_t off_slots = off_oc + 256;                      // 131328
    const size_t off_ovf   = off_slots + (size_t)NBINS * CAP * 4;
    const size_t need      = off_ovf + (size_t)N * 4;

    if (ws_size < need || N <= 0) {
        const int block = 256;
        const long long total = 2LL * N;
        const int grid = (int)((total + block - 1) / block);
        if (grid > 0)
            hipLaunchKernelGGL(ngp_hash_interp2, dim3(grid), dim3(block), 0, stream,
                               pts, feat4, out4, N, buckets, is_pow2);
        return;
    }

    unsigned* count  = (unsigned*)((char*)d_ws + off_count);
    unsigned* ocount = (unsigned*)((char*)d_ws + off_oc);
    unsigned* slots  = (unsigned*)((char*)d_ws + off_slots);
    unsigned* ovf    = (unsigned*)((char*)d_ws + off_ovf);

    hipMemsetAsync(d_ws, 0, off_oc + 4, stream);   // clear count + ocount

    const int block = 256;
    int gridN = (N + block - 1) / block;
    hipLaunchKernelGGL(scatter_bin_kernel, dim3(gridN), dim3(block), 0, stream,
                       pts, count, ocount, slots, ovf, N);
    hipLaunchKernelGGL(main_sorted_kernel, dim3(NBINS), dim3(MAIN_BLOCK), 0, stream,
                       pts, count, slots, feat4, out4, buckets, is_pow2);
    hipLaunchKernelGGL(overflow_kernel, dim3(512), dim3(256), 0, stream,
                       pts, ocount, ovf, feat4, out4, buckets, is_pow2);
}